// Round 6
// baseline (203.770 us; speedup 1.0000x reference)
//
#include <hip/hip_runtime.h>
#include <hip/hip_bf16.h>

typedef __attribute__((ext_vector_type(8))) short bf16x8;
typedef __attribute__((ext_vector_type(4))) float f32x4;
typedef __attribute__((ext_vector_type(16))) float f32x16;
typedef unsigned short u16;
typedef unsigned int u32;

#define NUM_HEAD 16
#define HEAD_DIM 64
#define SEQ_N 2048
#define SEQ_K 2048
#define EMB 1024
#define MROWS 4096          // B*N == B*K
// HEAD_DIM^-0.5 * log2(e): Q pre-scaled so softmax uses raw v_exp_f32 (exp2)
static constexpr float ATTN_SCALE_LOG2E = 0.125f * 1.44269504f;

// bare v_exp_f32 — libm exp2f has a denormal fixup path (+13% VALUBusy, R5)
#if __has_builtin(__builtin_amdgcn_exp2f)
#define EXP2(x) __builtin_amdgcn_exp2f(x)
#else
#define EXP2(x) __expf(0.69314718056f * (x))
#endif

#if __has_builtin(__builtin_amdgcn_rcpf)
#define RCP(x) __builtin_amdgcn_rcpf(x)
#else
#define RCP(x) (1.0f / (x))
#endif

__device__ __forceinline__ u16 f2bf(float f) {
  __hip_bfloat16 h = __float2bfloat16(f);
  return *reinterpret_cast<u16*>(&h);
}

// packed f32 pair -> one u32 of 2 bf16 (lo in low half)
__device__ __forceinline__ u32 pack2(float lo, float hi) {
  __hip_bfloat162 h = __float22bfloat162_rn(make_float2(lo, hi));
  return *reinterpret_cast<u32*>(&h);
}

// v_permlane32_swap_b32: exchanges a.hi(lanes32-63) with b.lo(lanes0-31):
// a' = [a.lo | b.lo], b' = [a.hi | b.hi]
__device__ __forceinline__ void plswap(u32& a, u32& b) {
  auto r = __builtin_amdgcn_permlane32_swap(a, b, false, false);
  a = r[0]; b = r[1];
}

// async global->LDS 16B copy (global_load_lds_dwordx4); LDS dest must be
// wave-uniform base + lane*16 — staging layouts below are linear in tid.
// Global SOURCE is per-lane, so swizzled layouts = pre-swizzled source.
__device__ __forceinline__ void async16(const u16* g, u16* l) {
  __builtin_amdgcn_global_load_lds(
      (const __attribute__((address_space(1))) unsigned int*)g,
      (__attribute__((address_space(3))) unsigned int*)l, 16, 0, 0);
}

// ---------- fused fp32->bf16 convert for x and ctx (one dispatch) ----------
__global__ __launch_bounds__(256) void cvt2(const float* __restrict__ x,
                                            const float* __restrict__ ctx,
                                            u16* __restrict__ xb, u16* __restrict__ cb) {
  const int n4 = MROWS * EMB / 4;
  int gid = blockIdx.x * 256 + threadIdx.x;
  const float4* s; ushort4* d; int i;
  if (gid < n4) { s = (const float4*)x;   d = (ushort4*)xb; i = gid; }
  else          { s = (const float4*)ctx; d = (ushort4*)cb; i = gid - n4; }
  float4 v = s[i];
  ushort4 o;
  o.x = f2bf(v.x); o.y = f2bf(v.y); o.z = f2bf(v.z); o.w = f2bf(v.w);
  d[i] = o;
}

// ---------- fused transpose+convert of all 3 weights (grid.z selects) ------
__global__ __launch_bounds__(256) void transpose_cvt4(
    const float* __restrict__ Wq, const float* __restrict__ Wkv,
    const float* __restrict__ Wproj,
    u16* __restrict__ Wqt, u16* __restrict__ Wkvt, u16* __restrict__ Wpt) {
  __shared__ float tile[32][33];
  const int z = blockIdx.z;
  const float* W; u16* Wt; int srcN, colbase;
  if (z == 0)      { W = Wq;    Wt = Wqt;                          srcN = 1024; colbase = 0; }
  else if (z == 1) { W = Wkv;   Wt = Wkvt;                         srcN = 2048; colbase = 0; }
  else if (z == 2) { W = Wkv;   Wt = Wkvt + (size_t)1024 * 1024;   srcN = 2048; colbase = 1024; }
  else             { W = Wproj; Wt = Wpt;                          srcN = 1024; colbase = 0; }
  int n0 = blockIdx.x * 32, k0 = blockIdx.y * 32;
  int tx = threadIdx.x & 31, ty = threadIdx.x >> 5;
  #pragma unroll
  for (int i = ty; i < 32; i += 8)
    tile[i][tx] = W[(size_t)(k0 + i) * srcN + colbase + n0 + tx];
  __syncthreads();
  #pragma unroll
  for (int i = ty; i < 32; i += 8)
    Wt[(size_t)(n0 + i) * 1024 + k0 + tx] = f2bf(tile[tx][i]);
}

// ---------- fused Q + KV projection GEMM: m97-structure 128x128 ------------
// R5: 128x128 tile, BK=64, 4 waves of 64x64 (0.5 reads/MFMA),
// global_load_lds w=16, 3 blocks/CU (LDS 32KB).  grid (32 mb FAST, 24 nb
// SLOW): consecutive blocks share one 256KB B-panel (L2-resident per XCD).
// nb<8: Q.  nb>=8: KV (K->[B,H,K,hd]; V->[B,H,hd,K] barrier-free wave T).
__global__ __launch_bounds__(256, 3) void gemm_qkv(
    const u16* __restrict__ xb, const u16* __restrict__ cb,
    const u16* __restrict__ Wqt, const u16* __restrict__ Wkvt,
    const float* __restrict__ bq, const float* __restrict__ bkv,
    u16* __restrict__ Qb, u16* __restrict__ Kb, u16* __restrict__ Vtb)
{
  __shared__ alignas(16) u16 smem[(128 + 128) * 64];   // As then Bs (lds-linear)
  u16* As = smem;                   // 128 x 64
  u16* Bs = smem + 128 * 64;        // 128 x 64
  const int tid = threadIdx.x;
  const bool isQ = (blockIdx.y < 8);
  const int n0 = (isQ ? blockIdx.y : blockIdx.y - 8) * 128;
  const int m0 = blockIdx.x * 128;
  const u16* A      = isQ ? xb : cb;
  const u16* Wt     = isQ ? Wqt : Wkvt;
  const float* bias = isQ ? bq : bkv;
  const int wave = tid >> 6, lane = tid & 63;
  const int wm = (wave >> 1) * 64, wn = (wave & 1) * 64;
  const int l15 = lane & 15, quad = lane >> 4;

  f32x4 acc[4][4];
  #pragma unroll
  for (int i = 0; i < 4; i++)
    #pragma unroll
    for (int j = 0; j < 4; j++)
      #pragma unroll
      for (int r = 0; r < 4; r++) acc[i][j][r] = 0.0f;

  const int srow = tid >> 3;          // 0..31
  const int scol = (tid & 7) * 8;     // u16 col
  const u16* ag = A + (size_t)(m0 + srow) * EMB + scol;
  const u16* bg = Wt + (size_t)(n0 + srow) * EMB + scol;
  const int ldsoff = tid * 8;         // u16 units == tid*16 bytes (linear)

  for (int kt = 0; kt < EMB; kt += 64) {
    #pragma unroll
    for (int s = 0; s < 4; s++) {     // A,B: 4 shots x 32 rows each
      async16(ag + (size_t)(s * 32) * EMB + kt, &As[ldsoff + s * 2048]);
      async16(bg + (size_t)(s * 32) * EMB + kt, &Bs[ldsoff + s * 2048]);
    }
    __syncthreads();
    #pragma unroll
    for (int ks = 0; ks < 2; ks++) {
      bf16x8 af[4], bfr[4];
      #pragma unroll
      for (int i = 0; i < 4; i++)
        af[i]  = *(const bf16x8*)&As[(wm + i * 16 + l15) * 64 + ks * 32 + quad * 8];
      #pragma unroll
      for (int j = 0; j < 4; j++)
        bfr[j] = *(const bf16x8*)&Bs[(wn + j * 16 + l15) * 64 + ks * 32 + quad * 8];
      #pragma unroll
      for (int i = 0; i < 4; i++)
        #pragma unroll
        for (int j = 0; j < 4; j++)
          acc[i][j] = __builtin_amdgcn_mfma_f32_16x16x32_bf16(af[i], bfr[j], acc[i][j], 0, 0, 0);
    }
    __syncthreads();
  }

  // ---------------- epilogue ----------------
  const int h = ((n0 + wn) >> 6) & 15;      // wave-uniform head
  if (isQ) {
    #pragma unroll
    for (int j = 0; j < 4; j++) {
      const int gc = n0 + wn + j * 16 + l15;
      const float bv = bias[gc];
      const int d = j * 16 + l15;           // d within head (n0+wn 64-aligned)
      #pragma unroll
      for (int i = 0; i < 4; i++) {
        #pragma unroll
        for (int r = 0; r < 4; r++) {
          const int gm = m0 + wm + i * 16 + quad * 4 + r;
          const int bb = gm >> 11, nn = gm & 2047;
          Qb[((size_t)(bb * NUM_HEAD + h) * SEQ_N + nn) * HEAD_DIM + d] =
              f2bf((acc[i][j][r] + bv) * ATTN_SCALE_LOG2E);
        }
      }
    }
  } else if ((n0 >> 10) == 0) {  // K half -> [B,H,K,hd]
    #pragma unroll
    for (int j = 0; j < 4; j++) {
      const int gc = n0 + wn + j * 16 + l15;
      const float bv = bias[gc];
      const int d = j * 16 + l15;
      #pragma unroll
      for (int i = 0; i < 4; i++) {
        #pragma unroll
        for (int r = 0; r < 4; r++) {
          const int gm = m0 + wm + i * 16 + quad * 4 + r;
          const int bb = gm >> 11, kk = gm & 2047;
          Kb[((size_t)(bb * NUM_HEAD + h) * SEQ_K + kk) * HEAD_DIM + d] =
              f2bf(acc[i][j][r] + bv);
        }
      }
    }
  } else {  // V half: wave tile = 64 keys x 64 d (1 head); barrier-free LDS T
    u16* wbuf = smem + wave * 1088;     // 16 x 68 u16 per wave (wave-private)
    const int gm0 = m0 + wm;
    const int bb = gm0 >> 11;
    const int kk0 = gm0 & 2047;
    #pragma unroll
    for (int j = 0; j < 4; j++) {       // d-chunks of 16
      const int gc = n0 + wn + j * 16 + l15;
      const float bv = bias[gc];
      #pragma unroll
      for (int i = 0; i < 4; i++) {     // key-chunks of 16
        ushort4 pk;
        pk.x = f2bf(acc[i][j][0] + bv);
        pk.y = f2bf(acc[i][j][1] + bv);
        pk.z = f2bf(acc[i][j][2] + bv);
        pk.w = f2bf(acc[i][j][3] + bv);
        // transposed in-place: row = d (l15), col = key (i*16+quad*4+r)
        *(ushort4*)&wbuf[l15 * 68 + i * 16 + quad * 4] = pk;
      }
      // read d-major rows, store 128B key-runs (in-order DS per wave; the
      // compiler inserts lgkmcnt for the aliasing wbuf pointer — no barrier)
      #pragma unroll
      for (int it = 0; it < 2; it++) {
        const int dd = it * 8 + (lane >> 3);   // 0..15
        const int kp = (lane & 7) * 8;         // 0..56
        uint4 v = *(const uint4*)&wbuf[dd * 68 + kp];
        *(uint4*)(Vtb + ((size_t)(bb * NUM_HEAD + h) * HEAD_DIM + j * 16 + dd) * SEQ_K
                  + kk0 + kp) = v;
      }
    }
  }
}

// ---------- out-projection GEMM: 64x128 tile, (mb FAST, nb SLOW) -----------
__global__ __launch_bounds__(256) void gemm_proj(
    const u16* __restrict__ A, const u16* __restrict__ Wt,
    const float* __restrict__ bias, float* __restrict__ outF)
{
  __shared__ alignas(16) u16 smem[(64 + 128) * 64];
  u16* As = smem;                 // 64 x 64
  u16* Bs = smem + 64 * 64;       // 128 x 64
  const int tid = threadIdx.x;
  const int n0 = blockIdx.y * 128, m0 = blockIdx.x * 64;
  const int wave = tid >> 6, lane = tid & 63;
  const int wm = (wave >> 1) * 32, wn = (wave & 1) * 64;
  const int l15 = lane & 15, quad = lane >> 4;

  f32x4 acc[2][4];
  #pragma unroll
  for (int i = 0; i < 2; i++)
    #pragma unroll
    for (int j = 0; j < 4; j++)
      #pragma unroll
      for (int r = 0; r < 4; r++) acc[i][j][r] = 0.0f;

  const int srow = tid >> 3;
  const int scol = (tid & 7) * 8;
  const u16* ag = A + (size_t)(m0 + srow) * EMB + scol;
  const u16* bg = Wt + (size_t)(n0 + srow) * EMB + scol;
  const int ldsoff = tid * 8;

  for (int kt = 0; kt < EMB; kt += 64) {
    async16(ag + kt, &As[ldsoff]);
    async16(ag + (size_t)32 * EMB + kt, &As[ldsoff + 2048]);
    #pragma unroll
    for (int s = 0; s < 4; s++)
      async16(bg + (size_t)(s * 32) * EMB + kt, &Bs[ldsoff + s * 2048]);
    __syncthreads();
    #pragma unroll
    for (int ks = 0; ks < 2; ks++) {
      bf16x8 af[2], bfr[4];
      #pragma unroll
      for (int i = 0; i < 2; i++)
        af[i]  = *(const bf16x8*)&As[(wm + i * 16 + l15) * 64 + ks * 32 + quad * 8];
      #pragma unroll
      for (int j = 0; j < 4; j++)
        bfr[j] = *(const bf16x8*)&Bs[(wn + j * 16 + l15) * 64 + ks * 32 + quad * 8];
      #pragma unroll
      for (int i = 0; i < 2; i++)
        #pragma unroll
        for (int j = 0; j < 4; j++)
          acc[i][j] = __builtin_amdgcn_mfma_f32_16x16x32_bf16(af[i], bfr[j], acc[i][j], 0, 0, 0);
    }
    __syncthreads();
  }

  #pragma unroll
  for (int i = 0; i < 2; i++) {
    #pragma unroll
    for (int j = 0; j < 4; j++) {
      const int gc = n0 + wn + j * 16 + l15;
      const float bv = bias[gc];
      #pragma unroll
      for (int r = 0; r < 4; r++) {
        const int gm = m0 + wm + i * 16 + quad * 4 + r;
        outF[(size_t)gm * EMB + gc] = acc[i][j][r] + bv;
      }
    }
  }
}

// ------------- flash attention: swapped-QK^T 32x32, P in registers -------------
// R6 (instruction-count cut; structure from R4 kept: 4 waves x 32 q-rows,
// 2 blocks/CU, KT=128, DMA-staged dbuf K/V, both-sides XOR swizzle):
//  - zero-C hoist: each group's first QK MFMA takes a loop-invariant zero
//    f32x16 as C — kills 64 v_mov zero-inits per iter (~19% of VALU stream).
//  - denominator via ones-column MFMA: od = mfma(pa, ones_B, od) with a
//    constant bf16-1.0 B frag (no LDS read).  Every column of od = P-row
//    sum, same C-layout as o0/o1 -> epilogue is per-reg rcp, ZERO shuffles.
//    Kills 64 VALU adds/iter + the end-of-kernel cross-lane fold; costs
//    8 MFMA/iter on the under-used MFMA pipe.  O and l now both derive
//    from the same bf16-rounded P (more self-consistent numerics).
//  - PV MFMAs alternate o0/o1/od: no back-to-back dependent accumulates.
__global__ __launch_bounds__(256, 2) void attn_kernel(
    const u16* __restrict__ Qb, const u16* __restrict__ Kb,
    const u16* __restrict__ Vtb, u16* __restrict__ Ob)
{
  __shared__ alignas(16) u16 Ks[2][128 * 64];   // [key][d], pitch 128B, 3-bit swz
  __shared__ alignas(16) u16 Vs[2][64 * 128];   // [d][key], pitch 256B, 4-bit swz
  const int tid = threadIdx.x;
  const int bh = blockIdx.x;
  const int m0 = blockIdx.y * 128;
  const int wave = tid >> 6, lane = tid & 63;
  const int l31 = lane & 31, hi = lane >> 5;
  const int hi16 = hi * 16;               // byte offset of k-half in a frag row
  const int swzK = (l31 & 7) << 4;        // K read-side XOR (row&7 == l31&7)
  const int swzV = (l31 & 15) << 4;       // V read-side XOR (d&15 == l31&15)
  const int rowb = m0 + wave * 32;

  // Q as B-operand frags for 32x32x16: lane holds col qrow=l31, k=d=db*16+hi*8+e
  bf16x8 bq[4];
  {
    const u16* qp = Qb + ((size_t)bh * SEQ_N + rowb + l31) * HEAD_DIM + hi * 8;
    #pragma unroll
    for (int db = 0; db < 4; db++) bq[db] = *(const bf16x8*)(qp + db * 16);
  }

  f32x16 o0, o1, od;                      // O d 0..31 / 32..63 / denominator
  #pragma unroll
  for (int r = 0; r < 16; r++) { o0[r] = 0.f; o1[r] = 0.f; od[r] = 0.f; }
  f32x16 zc;                              // loop-invariant zero C operand
  #pragma unroll
  for (int r = 0; r < 16; r++) zc[r] = 0.f;
  union { u32 u[4]; bf16x8 v; } ones;     // constant bf16 1.0 B frag
  ones.u[0] = ones.u[1] = ones.u[2] = ones.u[3] = 0x3F803F80u;

  // DMA staging: 256 threads x 16B x 4 shots = one 16KB matrix tile per macro.
  const int krow0 = tid >> 3;                      // 0..31 (K shot row)
  const int ksg   = (tid & 7) ^ (krow0 & 7);       // pre-swizzled K src granule
  const int vrow0 = tid >> 4;                      // 0..15 (V shot d-row)
  const int vsg   = (tid & 15) ^ vrow0;            // pre-swizzled V src granule
  const u16* kg = Kb  + (size_t)bh * SEQ_K * HEAD_DIM;   // [k][d]
  const u16* vg = Vtb + (size_t)bh * HEAD_DIM * SEQ_K;   // [d][k]

#define STAGE(kt_, nb_) do {                                                   \
    _Pragma("unroll")                                                          \
    for (int s = 0; s < 4; s++) {                                              \
      async16(kg + (size_t)((kt_) + s * 32 + krow0) * HEAD_DIM + ksg * 8,      \
              &Ks[nb_][s * 2048 + tid * 8]);                                   \
      async16(vg + (size_t)(s * 16 + vrow0) * SEQ_K + (kt_) + vsg * 8,         \
              &Vs[nb_][s * 2048 + tid * 8]);                                   \
    }                                                                          \
  } while (0)

  STAGE(0, 0);
  __syncthreads();   // implicit vmcnt(0) drains the DMA

  for (int kt = 0; kt < SEQ_K; kt += 128) {
    const int cur = (kt >> 7) & 1;
    if (kt + 128 < SEQ_K) STAGE(kt + 128, cur ^ 1);  // lands under this iter
    const char* KsB = (const char*)Ks[cur];
    const char* VsB = (const char*)Vs[cur];

    #pragma unroll
    for (int g = 0; g < 4; g++) {
      // ---- S^T = K·Q^T: first MFMA consumes zc (no per-iter zero-init) ----
      __builtin_amdgcn_s_setprio(1);
      bf16x8 ka = *(const bf16x8*)(KsB + (g * 32 + l31) * 128 + (hi16 ^ swzK));
      f32x16 s = __builtin_amdgcn_mfma_f32_32x32x16_bf16(ka, bq[0], zc, 0, 0, 0);
      #pragma unroll
      for (int db = 1; db < 4; db++) {
        ka = *(const bf16x8*)(KsB + (g * 32 + l31) * 128 + ((db * 32 + hi16) ^ swzK));
        s = __builtin_amdgcn_mfma_f32_32x32x16_bf16(ka, bq[db], s, 0, 0, 0);
      }
      __builtin_amdgcn_s_setprio(0);

      // ---- exp2 + pack to bf16 PV A-frags (T12); denom comes via MFMA ----
      float p[16];
      #pragma unroll
      for (int r = 0; r < 16; r++) p[r] = EXP2(s[r]);
      u32 w0 = pack2(p[0],  p[1]),  w1 = pack2(p[2],  p[3]);
      u32 w2 = pack2(p[4],  p[5]),  w3 = pack2(p[6],  p[7]);
      u32 w4 = pack2(p[8],  p[9]),  w5 = pack2(p[10], p[11]);
      u32 w6 = pack2(p[12], p[13]), w7 = pack2(p[14], p[15]);
      plswap(w0, w2); plswap(w1, w3);   // kslot 0: keys hi*8 + 0..7
      plswap(w4, w6); plswap(w5, w7);   // kslot 1: keys 16 + hi*8 + 0..7
      union PU { u32 u[4]; bf16x8 v; } pa0, pa1;
      pa0.u[0] = w0; pa0.u[1] = w1; pa0.u[2] = w2; pa0.u[3] = w3;
      pa1.u[0] = w4; pa1.u[1] = w5; pa1.u[2] = w6; pa1.u[3] = w7;

      // ---- O += P·V and od += P·1, alternating accumulators ----
      __builtin_amdgcn_s_setprio(1);
      bf16x8 vb00 = *(const bf16x8*)(VsB + (l31)*256      + ((g * 64 + hi16)      ^ swzV));
      bf16x8 vb01 = *(const bf16x8*)(VsB + (l31)*256      + ((g * 64 + 32 + hi16) ^ swzV));
      bf16x8 vb10 = *(const bf16x8*)(VsB + (32 + l31)*256 + ((g * 64 + hi16)      ^ swzV));
      bf16x8 vb11 = *(const bf16x8*)(VsB + (32 + l31)*256 + ((g * 64 + 32 + hi16) ^ swzV));
      o0 = __builtin_amdgcn_mfma_f32_32x32x16_bf16(pa0.v, vb00, o0, 0, 0, 0);
      o1 = __builtin_amdgcn_mfma_f32_32x32x16_bf16(pa0.v, vb10, o1, 0, 0, 0);
      od = __builtin_amdgcn_mfma_f32_32x32x16_bf16(pa0.v, ones.v, od, 0, 0, 0);
      o0 = __builtin_amdgcn_mfma_f32_32x32x16_bf16(pa1.v, vb01, o0, 0, 0, 0);
      o1 = __builtin_amdgcn_mfma_f32_32x32x16_bf16(pa1.v, vb11, o1, 0, 0, 0);
      od = __builtin_amdgcn_mfma_f32_32x32x16_bf16(pa1.v, ones.v, od, 0, 0, 0);
      __builtin_amdgcn_s_setprio(0);
    }
    __syncthreads();  // closes reads of cur + drains DMA into cur^1
  }
#undef STAGE

  // od[r] = full softmax denominator of q-row crow(r,hi) (all cols equal)
  const int bb = bh >> 4, hh = bh & 15;
  #pragma unroll
  for (int r = 0; r < 16; r++) {
    const int qrow = (r & 3) + 8 * (r >> 2) + 4 * hi;   // C-row of reg r
    const float invr = RCP(od[r]);
    const int gm = rowb + qrow;
    u16* op = Ob + ((size_t)bb * SEQ_N + gm) * EMB + hh * HEAD_DIM + l31;
    op[0]  = f2bf(o0[r] * invr);
    op[32] = f2bf(o1[r] * invr);
  }
}

extern "C" void kernel_launch(void* const* d_in, const int* in_sizes, int n_in,
                              void* d_out, int out_size, void* d_ws, size_t ws_size,
                              hipStream_t stream)
{
  const float* x     = (const float*)d_in[0];
  const float* ctx   = (const float*)d_in[1];
  const float* Wq    = (const float*)d_in[2];
  const float* bq    = (const float*)d_in[3];
  const float* Wkv   = (const float*)d_in[4];
  const float* bkv   = (const float*)d_in[5];
  const float* Wproj = (const float*)d_in[6];
  const float* bproj = (const float*)d_in[7];
  float* out = (float*)d_out;

  char* ws = (char*)d_ws;
  size_t off = 0;
  auto walloc = [&](size_t bytes) -> void* {
    void* p = ws + off;
    off += (bytes + 255) & ~(size_t)255;
    return p;
  };
  u16* xb   = (u16*)walloc((size_t)MROWS * EMB * 2);
  u16* cb   = (u16*)walloc((size_t)MROWS * EMB * 2);
  u16* Wqt  = (u16*)walloc((size_t)EMB * EMB * 2);
  u16* Wkvt = (u16*)walloc((size_t)2 * EMB * EMB * 2);
  u16* Wpt  = (u16*)walloc((size_t)EMB * EMB * 2);
  u16* Qb   = (u16*)walloc((size_t)MROWS * EMB * 2);
  u16* Kb   = (u16*)walloc((size_t)MROWS * EMB * 2);
  u16* Vtb  = (u16*)walloc((size_t)MROWS * EMB * 2);
  u16* Ob   = (u16*)walloc((size_t)MROWS * EMB * 2);

  cvt2<<<8192, 256, 0, stream>>>(x, ctx, xb, cb);
  transpose_cvt4<<<dim3(32, 32, 4), 256, 0, stream>>>(Wq, Wkv, Wproj, Wqt, Wkvt, Wpt);
  gemm_qkv<<<dim3(32, 24), 256, 0, stream>>>(xb, cb, Wqt, Wkvt, bq, bkv, Qb, Kb, Vtb);
  attn_kernel<<<dim3(32, 16), 256, 0, stream>>>(Qb, Kb, Vtb, Ob);
  gemm_proj<<<dim3(64, 8), 256, 0, stream>>>(Ob, Wpt, bproj, out);
}

// Round 7
// 202.756 us; speedup vs baseline: 1.0050x; 1.0050x over previous
//
#include <hip/hip_runtime.h>
#include <hip/hip_bf16.h>

typedef __attribute__((ext_vector_type(8))) short bf16x8;
typedef __attribute__((ext_vector_type(4))) float f32x4;
typedef __attribute__((ext_vector_type(16))) float f32x16;
typedef unsigned short u16;
typedef unsigned int u32;

#define NUM_HEAD 16
#define HEAD_DIM 64
#define SEQ_N 2048
#define SEQ_K 2048
#define EMB 1024
#define MROWS 4096          // B*N == B*K
// HEAD_DIM^-0.5 * log2(e): Q pre-scaled so softmax uses raw v_exp_f32 (exp2)
static constexpr float ATTN_SCALE_LOG2E = 0.125f * 1.44269504f;

// bare v_exp_f32 — libm exp2f has a denormal fixup path (+13% VALUBusy, R5)
#if __has_builtin(__builtin_amdgcn_exp2f)
#define EXP2(x) __builtin_amdgcn_exp2f(x)
#else
#define EXP2(x) __expf(0.69314718056f * (x))
#endif

#if __has_builtin(__builtin_amdgcn_rcpf)
#define RCP(x) __builtin_amdgcn_rcpf(x)
#else
#define RCP(x) (1.0f / (x))
#endif

#define SGB __builtin_amdgcn_sched_group_barrier

__device__ __forceinline__ u16 f2bf(float f) {
  __hip_bfloat16 h = __float2bfloat16(f);
  return *reinterpret_cast<u16*>(&h);
}

// packed f32 pair -> one u32 of 2 bf16 (lo in low half)
__device__ __forceinline__ u32 pack2(float lo, float hi) {
  __hip_bfloat162 h = __float22bfloat162_rn(make_float2(lo, hi));
  return *reinterpret_cast<u32*>(&h);
}

// v_permlane32_swap_b32: exchanges a.hi(lanes32-63) with b.lo(lanes0-31):
// a' = [a.lo | b.lo], b' = [a.hi | b.hi]
__device__ __forceinline__ void plswap(u32& a, u32& b) {
  auto r = __builtin_amdgcn_permlane32_swap(a, b, false, false);
  a = r[0]; b = r[1];
}

// async global->LDS 16B copy (global_load_lds_dwordx4); LDS dest must be
// wave-uniform base + lane*16 — staging layouts below are linear in tid.
// Global SOURCE is per-lane, so swizzled layouts = pre-swizzled source.
__device__ __forceinline__ void async16(const u16* g, u16* l) {
  __builtin_amdgcn_global_load_lds(
      (const __attribute__((address_space(1))) unsigned int*)g,
      (__attribute__((address_space(3))) unsigned int*)l, 16, 0, 0);
}

// ---------- fused fp32->bf16 convert for x and ctx (one dispatch) ----------
__global__ __launch_bounds__(256) void cvt2(const float* __restrict__ x,
                                            const float* __restrict__ ctx,
                                            u16* __restrict__ xb, u16* __restrict__ cb) {
  const int n4 = MROWS * EMB / 4;
  int gid = blockIdx.x * 256 + threadIdx.x;
  const float4* s; ushort4* d; int i;
  if (gid < n4) { s = (const float4*)x;   d = (ushort4*)xb; i = gid; }
  else          { s = (const float4*)ctx; d = (ushort4*)cb; i = gid - n4; }
  float4 v = s[i];
  ushort4 o;
  o.x = f2bf(v.x); o.y = f2bf(v.y); o.z = f2bf(v.z); o.w = f2bf(v.w);
  d[i] = o;
}

// ---------- fused transpose+convert of all 3 weights (grid.z selects) ------
__global__ __launch_bounds__(256) void transpose_cvt4(
    const float* __restrict__ Wq, const float* __restrict__ Wkv,
    const float* __restrict__ Wproj,
    u16* __restrict__ Wqt, u16* __restrict__ Wkvt, u16* __restrict__ Wpt) {
  __shared__ float tile[32][33];
  const int z = blockIdx.z;
  const float* W; u16* Wt; int srcN, colbase;
  if (z == 0)      { W = Wq;    Wt = Wqt;                          srcN = 1024; colbase = 0; }
  else if (z == 1) { W = Wkv;   Wt = Wkvt;                         srcN = 2048; colbase = 0; }
  else if (z == 2) { W = Wkv;   Wt = Wkvt + (size_t)1024 * 1024;   srcN = 2048; colbase = 1024; }
  else             { W = Wproj; Wt = Wpt;                          srcN = 1024; colbase = 0; }
  int n0 = blockIdx.x * 32, k0 = blockIdx.y * 32;
  int tx = threadIdx.x & 31, ty = threadIdx.x >> 5;
  #pragma unroll
  for (int i = ty; i < 32; i += 8)
    tile[i][tx] = W[(size_t)(k0 + i) * srcN + colbase + n0 + tx];
  __syncthreads();
  #pragma unroll
  for (int i = ty; i < 32; i += 8)
    Wt[(size_t)(n0 + i) * 1024 + k0 + tx] = f2bf(tile[tx][i]);
}

// ---------- fused Q + KV projection GEMM: m97-structure 128x128 ------------
// R5: 128x128 tile, BK=64, 4 waves of 64x64 (0.5 reads/MFMA),
// global_load_lds w=16, 3 blocks/CU (LDS 32KB).  grid (32 mb FAST, 24 nb
// SLOW): consecutive blocks share one 256KB B-panel (L2-resident per XCD).
// nb<8: Q.  nb>=8: KV (K->[B,H,K,hd]; V->[B,H,hd,K] barrier-free wave T).
__global__ __launch_bounds__(256, 3) void gemm_qkv(
    const u16* __restrict__ xb, const u16* __restrict__ cb,
    const u16* __restrict__ Wqt, const u16* __restrict__ Wkvt,
    const float* __restrict__ bq, const float* __restrict__ bkv,
    u16* __restrict__ Qb, u16* __restrict__ Kb, u16* __restrict__ Vtb)
{
  __shared__ alignas(16) u16 smem[(128 + 128) * 64];   // As then Bs (lds-linear)
  u16* As = smem;                   // 128 x 64
  u16* Bs = smem + 128 * 64;        // 128 x 64
  const int tid = threadIdx.x;
  const bool isQ = (blockIdx.y < 8);
  const int n0 = (isQ ? blockIdx.y : blockIdx.y - 8) * 128;
  const int m0 = blockIdx.x * 128;
  const u16* A      = isQ ? xb : cb;
  const u16* Wt     = isQ ? Wqt : Wkvt;
  const float* bias = isQ ? bq : bkv;
  const int wave = tid >> 6, lane = tid & 63;
  const int wm = (wave >> 1) * 64, wn = (wave & 1) * 64;
  const int l15 = lane & 15, quad = lane >> 4;

  f32x4 acc[4][4];
  #pragma unroll
  for (int i = 0; i < 4; i++)
    #pragma unroll
    for (int j = 0; j < 4; j++)
      #pragma unroll
      for (int r = 0; r < 4; r++) acc[i][j][r] = 0.0f;

  const int srow = tid >> 3;          // 0..31
  const int scol = (tid & 7) * 8;     // u16 col
  const u16* ag = A + (size_t)(m0 + srow) * EMB + scol;
  const u16* bg = Wt + (size_t)(n0 + srow) * EMB + scol;
  const int ldsoff = tid * 8;         // u16 units == tid*16 bytes (linear)

  for (int kt = 0; kt < EMB; kt += 64) {
    #pragma unroll
    for (int s = 0; s < 4; s++) {     // A,B: 4 shots x 32 rows each
      async16(ag + (size_t)(s * 32) * EMB + kt, &As[ldsoff + s * 2048]);
      async16(bg + (size_t)(s * 32) * EMB + kt, &Bs[ldsoff + s * 2048]);
    }
    __syncthreads();
    #pragma unroll
    for (int ks = 0; ks < 2; ks++) {
      bf16x8 af[4], bfr[4];
      #pragma unroll
      for (int i = 0; i < 4; i++)
        af[i]  = *(const bf16x8*)&As[(wm + i * 16 + l15) * 64 + ks * 32 + quad * 8];
      #pragma unroll
      for (int j = 0; j < 4; j++)
        bfr[j] = *(const bf16x8*)&Bs[(wn + j * 16 + l15) * 64 + ks * 32 + quad * 8];
      #pragma unroll
      for (int i = 0; i < 4; i++)
        #pragma unroll
        for (int j = 0; j < 4; j++)
          acc[i][j] = __builtin_amdgcn_mfma_f32_16x16x32_bf16(af[i], bfr[j], acc[i][j], 0, 0, 0);
    }
    __syncthreads();
  }

  // ---------------- epilogue ----------------
  const int h = ((n0 + wn) >> 6) & 15;      // wave-uniform head
  if (isQ) {
    #pragma unroll
    for (int j = 0; j < 4; j++) {
      const int gc = n0 + wn + j * 16 + l15;
      const float bv = bias[gc];
      const int d = j * 16 + l15;           // d within head (n0+wn 64-aligned)
      #pragma unroll
      for (int i = 0; i < 4; i++) {
        #pragma unroll
        for (int r = 0; r < 4; r++) {
          const int gm = m0 + wm + i * 16 + quad * 4 + r;
          const int bb = gm >> 11, nn = gm & 2047;
          Qb[((size_t)(bb * NUM_HEAD + h) * SEQ_N + nn) * HEAD_DIM + d] =
              f2bf((acc[i][j][r] + bv) * ATTN_SCALE_LOG2E);
        }
      }
    }
  } else if ((n0 >> 10) == 0) {  // K half -> [B,H,K,hd]
    #pragma unroll
    for (int j = 0; j < 4; j++) {
      const int gc = n0 + wn + j * 16 + l15;
      const float bv = bias[gc];
      const int d = j * 16 + l15;
      #pragma unroll
      for (int i = 0; i < 4; i++) {
        #pragma unroll
        for (int r = 0; r < 4; r++) {
          const int gm = m0 + wm + i * 16 + quad * 4 + r;
          const int bb = gm >> 11, kk = gm & 2047;
          Kb[((size_t)(bb * NUM_HEAD + h) * SEQ_K + kk) * HEAD_DIM + d] =
              f2bf(acc[i][j][r] + bv);
        }
      }
    }
  } else {  // V half: wave tile = 64 keys x 64 d (1 head); barrier-free LDS T
    u16* wbuf = smem + wave * 1088;     // 16 x 68 u16 per wave (wave-private)
    const int gm0 = m0 + wm;
    const int bb = gm0 >> 11;
    const int kk0 = gm0 & 2047;
    #pragma unroll
    for (int j = 0; j < 4; j++) {       // d-chunks of 16
      const int gc = n0 + wn + j * 16 + l15;
      const float bv = bias[gc];
      #pragma unroll
      for (int i = 0; i < 4; i++) {     // key-chunks of 16
        ushort4 pk;
        pk.x = f2bf(acc[i][j][0] + bv);
        pk.y = f2bf(acc[i][j][1] + bv);
        pk.z = f2bf(acc[i][j][2] + bv);
        pk.w = f2bf(acc[i][j][3] + bv);
        // transposed in-place: row = d (l15), col = key (i*16+quad*4+r)
        *(ushort4*)&wbuf[l15 * 68 + i * 16 + quad * 4] = pk;
      }
      // read d-major rows, store 128B key-runs (in-order DS per wave; the
      // compiler inserts lgkmcnt for the aliasing wbuf pointer — no barrier)
      #pragma unroll
      for (int it = 0; it < 2; it++) {
        const int dd = it * 8 + (lane >> 3);   // 0..15
        const int kp = (lane & 7) * 8;         // 0..56
        uint4 v = *(const uint4*)&wbuf[dd * 68 + kp];
        *(uint4*)(Vtb + ((size_t)(bb * NUM_HEAD + h) * HEAD_DIM + j * 16 + dd) * SEQ_K
                  + kk0 + kp) = v;
      }
    }
  }
}

// ---------- out-projection GEMM: 64x128 tile, (mb FAST, nb SLOW) -----------
__global__ __launch_bounds__(256) void gemm_proj(
    const u16* __restrict__ A, const u16* __restrict__ Wt,
    const float* __restrict__ bias, float* __restrict__ outF)
{
  __shared__ alignas(16) u16 smem[(64 + 128) * 64];
  u16* As = smem;                 // 64 x 64
  u16* Bs = smem + 64 * 64;       // 128 x 64
  const int tid = threadIdx.x;
  const int n0 = blockIdx.y * 128, m0 = blockIdx.x * 64;
  const int wave = tid >> 6, lane = tid & 63;
  const int wm = (wave >> 1) * 32, wn = (wave & 1) * 64;
  const int l15 = lane & 15, quad = lane >> 4;

  f32x4 acc[2][4];
  #pragma unroll
  for (int i = 0; i < 2; i++)
    #pragma unroll
    for (int j = 0; j < 4; j++)
      #pragma unroll
      for (int r = 0; r < 4; r++) acc[i][j][r] = 0.0f;

  const int srow = tid >> 3;
  const int scol = (tid & 7) * 8;
  const u16* ag = A + (size_t)(m0 + srow) * EMB + scol;
  const u16* bg = Wt + (size_t)(n0 + srow) * EMB + scol;
  const int ldsoff = tid * 8;

  for (int kt = 0; kt < EMB; kt += 64) {
    async16(ag + kt, &As[ldsoff]);
    async16(ag + (size_t)32 * EMB + kt, &As[ldsoff + 2048]);
    #pragma unroll
    for (int s = 0; s < 4; s++)
      async16(bg + (size_t)(s * 32) * EMB + kt, &Bs[ldsoff + s * 2048]);
    __syncthreads();
    #pragma unroll
    for (int ks = 0; ks < 2; ks++) {
      bf16x8 af[2], bfr[4];
      #pragma unroll
      for (int i = 0; i < 2; i++)
        af[i]  = *(const bf16x8*)&As[(wm + i * 16 + l15) * 64 + ks * 32 + quad * 8];
      #pragma unroll
      for (int j = 0; j < 4; j++)
        bfr[j] = *(const bf16x8*)&Bs[(wn + j * 16 + l15) * 64 + ks * 32 + quad * 8];
      #pragma unroll
      for (int i = 0; i < 2; i++)
        #pragma unroll
        for (int j = 0; j < 4; j++)
          acc[i][j] = __builtin_amdgcn_mfma_f32_16x16x32_bf16(af[i], bfr[j], acc[i][j], 0, 0, 0);
    }
    __syncthreads();
  }

  #pragma unroll
  for (int i = 0; i < 2; i++) {
    #pragma unroll
    for (int j = 0; j < 4; j++) {
      const int gc = n0 + wn + j * 16 + l15;
      const float bv = bias[gc];
      #pragma unroll
      for (int r = 0; r < 4; r++) {
        const int gm = m0 + wm + i * 16 + quad * 4 + r;
        outF[(size_t)gm * EMB + gc] = acc[i][j][r] + bv;
      }
    }
  }
}

// ------------- flash attention: swapped-QK^T 32x32, P in registers -------------
// R7: explicit 2-deep software pipeline (att[2]/T15 + T19 pinning).
// R6 evidence: instruction-mix moved exactly as predicted, time did not
// (latency-bound at 2 waves/SIMD, ~5x slack vs pipe loads).  New inner loop:
// group g+1's K-frag reads + QK MFMAs are issued BEFORE group g's softmax
// (independent -> overlap), V-frag reads hoisted before softmax; schedule
// pinned with sched_group_barrier (DS_READ 0x100 / MFMA 0x8 / VALU 0x2) so
// hipcc cannot re-collapse it (as it did to R4's phase-A).  VGPR headroom is
// free: LDS (64KB dbuf) caps at 2 blocks/CU regardless (budget 256/wave).
// Kept from R4-R6: 4 waves x 32 q-rows, KT=128, DMA dbuf, XOR swizzle,
// zero-C hoist, ones-column MFMA denominator, alternating o0/o1/od.
__global__ __launch_bounds__(256, 2) void attn_kernel(
    const u16* __restrict__ Qb, const u16* __restrict__ Kb,
    const u16* __restrict__ Vtb, u16* __restrict__ Ob)
{
  __shared__ alignas(16) u16 Ks[2][128 * 64];   // [key][d], pitch 128B, 3-bit swz
  __shared__ alignas(16) u16 Vs[2][64 * 128];   // [d][key], pitch 256B, 4-bit swz
  const int tid = threadIdx.x;
  const int bh = blockIdx.x;
  const int m0 = blockIdx.y * 128;
  const int wave = tid >> 6, lane = tid & 63;
  const int l31 = lane & 31, hi = lane >> 5;
  const int hi16 = hi * 16;               // byte offset of k-half in a frag row
  const int swzK = (l31 & 7) << 4;        // K read-side XOR (row&7 == l31&7)
  const int swzV = (l31 & 15) << 4;       // V read-side XOR (d&15 == l31&15)
  const int rowb = m0 + wave * 32;

  // Q as B-operand frags for 32x32x16: lane holds col qrow=l31, k=d=db*16+hi*8+e
  bf16x8 bq[4];
  {
    const u16* qp = Qb + ((size_t)bh * SEQ_N + rowb + l31) * HEAD_DIM + hi * 8;
    #pragma unroll
    for (int db = 0; db < 4; db++) bq[db] = *(const bf16x8*)(qp + db * 16);
  }

  f32x16 o0, o1, od;                      // O d 0..31 / 32..63 / denominator
  #pragma unroll
  for (int r = 0; r < 16; r++) { o0[r] = 0.f; o1[r] = 0.f; od[r] = 0.f; }
  f32x16 zc;                              // loop-invariant zero C operand
  #pragma unroll
  for (int r = 0; r < 16; r++) zc[r] = 0.f;
  union { u32 u[4]; bf16x8 v; } ones;     // constant bf16 1.0 B frag
  ones.u[0] = ones.u[1] = ones.u[2] = ones.u[3] = 0x3F803F80u;

  // DMA staging: 256 threads x 16B x 4 shots = one 16KB matrix tile per macro.
  const int krow0 = tid >> 3;                      // 0..31 (K shot row)
  const int ksg   = (tid & 7) ^ (krow0 & 7);       // pre-swizzled K src granule
  const int vrow0 = tid >> 4;                      // 0..15 (V shot d-row)
  const int vsg   = (tid & 15) ^ vrow0;            // pre-swizzled V src granule
  const u16* kg = Kb  + (size_t)bh * SEQ_K * HEAD_DIM;   // [k][d]
  const u16* vg = Vtb + (size_t)bh * HEAD_DIM * SEQ_K;   // [d][k]

#define STAGE(kt_, nb_) do {                                                   \
    _Pragma("unroll")                                                          \
    for (int s = 0; s < 4; s++) {                                              \
      async16(kg + (size_t)((kt_) + s * 32 + krow0) * HEAD_DIM + ksg * 8,      \
              &Ks[nb_][s * 2048 + tid * 8]);                                   \
      async16(vg + (size_t)(s * 16 + vrow0) * SEQ_K + (kt_) + vsg * 8,         \
              &Vs[nb_][s * 2048 + tid * 8]);                                   \
    }                                                                          \
  } while (0)

  // QK of group g into dst (first MFMA consumes zc: no per-iter zero-init)
#define QKGRP(gg, dst) do {                                                    \
    bf16x8 ka_ = *(const bf16x8*)(KsB + ((gg) * 32 + l31) * 128 + (hi16 ^ swzK)); \
    dst = __builtin_amdgcn_mfma_f32_32x32x16_bf16(ka_, bq[0], zc, 0, 0, 0);    \
    _Pragma("unroll")                                                          \
    for (int db = 1; db < 4; db++) {                                           \
      ka_ = *(const bf16x8*)(KsB + ((gg) * 32 + l31) * 128 + ((db * 32 + hi16) ^ swzK)); \
      dst = __builtin_amdgcn_mfma_f32_32x32x16_bf16(ka_, bq[db], dst, 0, 0, 0); \
    }                                                                          \
  } while (0)

  STAGE(0, 0);
  __syncthreads();   // implicit vmcnt(0) drains the DMA

  for (int kt = 0; kt < SEQ_K; kt += 128) {
    const int cur = (kt >> 7) & 1;
    if (kt + 128 < SEQ_K) STAGE(kt + 128, cur ^ 1);  // lands under this iter
    const char* KsB = (const char*)Ks[cur];
    const char* VsB = (const char*)Vs[cur];

    f32x16 sA, sB;                 // 2-deep pipeline registers
    QKGRP(0, sA);                  // prologue: QK of group 0

    #pragma unroll
    for (int g = 0; g < 4; g++) {
      f32x16& sc = (g & 1) ? sB : sA;   // compile-time after full unroll
      f32x16& sn = (g & 1) ? sA : sB;

      // ---- early V-frag reads for THIS group (independent of sc) ----
      bf16x8 vb00 = *(const bf16x8*)(VsB + (l31)*256      + ((g * 64 + hi16)      ^ swzV));
      bf16x8 vb01 = *(const bf16x8*)(VsB + (l31)*256      + ((g * 64 + 32 + hi16) ^ swzV));
      bf16x8 vb10 = *(const bf16x8*)(VsB + (32 + l31)*256 + ((g * 64 + hi16)      ^ swzV));
      bf16x8 vb11 = *(const bf16x8*)(VsB + (32 + l31)*256 + ((g * 64 + 32 + hi16) ^ swzV));

      // ---- NEXT group's QK (independent of softmax below) ----
      if (g < 3) QKGRP(g + 1, sn);

      // ---- softmax of current group (VALU/TRANS, overlaps QK' MFMAs) ----
      float p[16];
      #pragma unroll
      for (int r = 0; r < 16; r++) p[r] = EXP2(sc[r]);
      u32 w0 = pack2(p[0],  p[1]),  w1 = pack2(p[2],  p[3]);
      u32 w2 = pack2(p[4],  p[5]),  w3 = pack2(p[6],  p[7]);
      u32 w4 = pack2(p[8],  p[9]),  w5 = pack2(p[10], p[11]);
      u32 w6 = pack2(p[12], p[13]), w7 = pack2(p[14], p[15]);
      plswap(w0, w2); plswap(w1, w3);   // kslot 0: keys hi*8 + 0..7
      plswap(w4, w6); plswap(w5, w7);   // kslot 1: keys 16 + hi*8 + 0..7
      union PU { u32 u[4]; bf16x8 v; } pa0, pa1;
      pa0.u[0] = w0; pa0.u[1] = w1; pa0.u[2] = w2; pa0.u[3] = w3;
      pa1.u[0] = w4; pa1.u[1] = w5; pa1.u[2] = w6; pa1.u[3] = w7;

      // ---- O += P·V and od += P·1, alternating accumulators ----
      o0 = __builtin_amdgcn_mfma_f32_32x32x16_bf16(pa0.v, vb00, o0, 0, 0, 0);
      o1 = __builtin_amdgcn_mfma_f32_32x32x16_bf16(pa0.v, vb10, o1, 0, 0, 0);
      od = __builtin_amdgcn_mfma_f32_32x32x16_bf16(pa0.v, ones.v, od, 0, 0, 0);
      o0 = __builtin_amdgcn_mfma_f32_32x32x16_bf16(pa1.v, vb01, o0, 0, 0, 0);
      o1 = __builtin_amdgcn_mfma_f32_32x32x16_bf16(pa1.v, vb11, o1, 0, 0, 0);
      od = __builtin_amdgcn_mfma_f32_32x32x16_bf16(pa1.v, ones.v, od, 0, 0, 0);

      // ---- pin the interleave (T19): ds_reads first, QK' MFMAs woven
      // through the softmax VALU stream, then PV cluster.  Counts are
      // soft targets — scheduler relaxes if a class runs dry. ----
      SGB(0x100, 8, 0);   // 4 V-frag + 4 K'-frag ds_reads
      SGB(0x008, 2, 0);   // 2 QK' MFMA
      SGB(0x002, 24, 0);  // exp2/pack chunk
      SGB(0x008, 2, 0);   // 2 QK' MFMA
      SGB(0x002, 24, 0);  // rest of softmax VALU
      SGB(0x008, 6, 0);   // 6 PV MFMA
    }
    __syncthreads();  // closes reads of cur + drains DMA into cur^1
  }
#undef QKGRP
#undef STAGE

  // od[r] = full softmax denominator of q-row crow(r,hi) (all cols equal)
  const int bb = bh >> 4, hh = bh & 15;
  #pragma unroll
  for (int r = 0; r < 16; r++) {
    const int qrow = (r & 3) + 8 * (r >> 2) + 4 * hi;   // C-row of reg r
    const float invr = RCP(od[r]);
    const int gm = rowb + qrow;
    u16* op = Ob + ((size_t)bb * SEQ_N + gm) * EMB + hh * HEAD_DIM + l31;
    op[0]  = f2bf(o0[r] * invr);
    op[32] = f2bf(o1[r] * invr);
  }
}

extern "C" void kernel_launch(void* const* d_in, const int* in_sizes, int n_in,
                              void* d_out, int out_size, void* d_ws, size_t ws_size,
                              hipStream_t stream)
{
  const float* x     = (const float*)d_in[0];
  const float* ctx   = (const float*)d_in[1];
  const float* Wq    = (const float*)d_in[2];
  const float* bq    = (const float*)d_in[3];
  const float* Wkv   = (const float*)d_in[4];
  const float* bkv   = (const float*)d_in[5];
  const float* Wproj = (const float*)d_in[6];
  const float* bproj = (const float*)d_in[7];
  float* out = (float*)d_out;

  char* ws = (char*)d_ws;
  size_t off = 0;
  auto walloc = [&](size_t bytes) -> void* {
    void* p = ws + off;
    off += (bytes + 255) & ~(size_t)255;
    return p;
  };
  u16* xb   = (u16*)walloc((size_t)MROWS * EMB * 2);
  u16* cb   = (u16*)walloc((size_t)MROWS * EMB * 2);
  u16* Wqt  = (u16*)walloc((size_t)EMB * EMB * 2);
  u16* Wkvt = (u16*)walloc((size_t)2 * EMB * EMB * 2);
  u16* Wpt  = (u16*)walloc((size_t)EMB * EMB * 2);
  u16* Qb   = (u16*)walloc((size_t)MROWS * EMB * 2);
  u16* Kb   = (u16*)walloc((size_t)MROWS * EMB * 2);
  u16* Vtb  = (u16*)walloc((size_t)MROWS * EMB * 2);
  u16* Ob   = (u16*)walloc((size_t)MROWS * EMB * 2);

  cvt2<<<8192, 256, 0, stream>>>(x, ctx, xb, cb);
  transpose_cvt4<<<dim3(32, 32, 4), 256, 0, stream>>>(Wq, Wkv, Wproj, Wqt, Wkvt, Wpt);
  gemm_qkv<<<dim3(32, 24), 256, 0, stream>>>(xb, cb, Wqt, Wkvt, bq, bkv, Qb, Kb, Vtb);
  attn_kernel<<<dim3(32, 16), 256, 0, stream>>>(Qb, Kb, Vtb, Ob);
  gemm_proj<<<dim3(64, 8), 256, 0, stream>>>(Ob, Wpt, bproj, out);
}